// Round 1
// baseline (329.235 us; speedup 1.0000x reference)
//
#include <hip/hip_runtime.h>
#include <hip/hip_bf16.h>

#define B_ 1024
#define P_ 8
#define D_ 2048
#define FD_ (P_ * D_)   // 16384
#define NID 64
#define MARGIN_ 0.3f
#define EPS_ 1e-12f

typedef unsigned short u16;
typedef short short8_t __attribute__((ext_vector_type(8)));
typedef float float4_t __attribute__((ext_vector_type(4)));

// ---------------- workspace layout (bytes) ----------------
// centers : 64*16384 fp32          = 4,194,304
// countsf : 64 fp32                = 256
// negcnt  : fp32                   (padded)
// possum  : fp32                   (padded)
// sq      : 1024*8 fp32            = 32,768
// dap     : 1024 fp32              = 4,096
// fb      : 1024*16384 bf16        = 33,554,432
// pd      : 2 * 1024*1024 fp32     = 8,388,608
static const size_t OFF_CENTERS = 0;
static const size_t OFF_COUNTS  = 4194304;
static const size_t OFF_NEG     = OFF_COUNTS + 256;
static const size_t OFF_POS     = OFF_NEG + 16;
static const size_t OFF_SQ      = OFF_POS + 16;                    // 4,194,592
static const size_t OFF_DAP     = OFF_SQ + (size_t)B_ * P_ * 4;    // 4,227,360
static const size_t OFF_FB      = OFF_DAP + (size_t)B_ * 4;        // 4,231,456 (16B aligned)
static const size_t OFF_PD      = OFF_FB + (size_t)B_ * FD_ * 2;   // 37,785,888

// ---------------- kernel 1: class counts + negative-pair count ----------------
__global__ void k_counts(const int* __restrict__ labels, float* countsf, float* negcnt) {
    int c = threadIdx.x;  // 64 threads
    int cnt = 0;
    for (int i = 0; i < B_; i++) cnt += (labels[i] == c) ? 1 : 0;
    countsf[c] = (float)cnt;
    __shared__ int scnt[NID];
    scnt[c] = cnt;
    __syncthreads();
    if (c == 0) {
        long long s = 0;
        for (int k = 0; k < NID; k++) s += (long long)scnt[k] * scnt[k];
        *negcnt = (float)((long long)B_ * B_ - s);
    }
}

// ---------------- kernel 2: segment-mean centers ----------------
// grid 256: class = bid>>2, feature chunk = bid&3 (4096 dims each); block 256
__global__ void k_centers(const float* __restrict__ feats, const int* __restrict__ labels,
                          const float* __restrict__ countsf, float* __restrict__ centers) {
    int cls   = blockIdx.x >> 2;
    int chunk = blockIdx.x & 3;
    int base  = chunk * 4096 + threadIdx.x;  // + k*256, k<16
    float acc[16];
#pragma unroll
    for (int k = 0; k < 16; k++) acc[k] = 0.f;
    for (int i = 0; i < B_; i++) {
        if (labels[i] == cls) {  // wave-uniform branch
            const float* row = feats + (size_t)i * FD_;
#pragma unroll
            for (int k = 0; k < 16; k++) acc[k] += row[base + k * 256];
        }
    }
    float inv = 1.0f / fmaxf(countsf[cls], 1.0f);
    float* crow = centers + (size_t)cls * FD_;
#pragma unroll
    for (int k = 0; k < 16; k++) crow[base + k * 256] = acc[k] * inv;
}

// ---------------- kernel 3: bf16 cast + sq + d_ap ----------------
// grid 1024 (one block per sample), block 256
__global__ void k_rowstats(const float* __restrict__ feats, const int* __restrict__ labels,
                           const float* __restrict__ centers, __hip_bfloat16* __restrict__ fb,
                           float* __restrict__ sq, float* __restrict__ dap) {
    int i = blockIdx.x;
    int tid = threadIdx.x;
    int lab = labels[i];
    const float* frow = feats + (size_t)i * FD_;
    const float* crow = centers + (size_t)lab * FD_;
    __hip_bfloat16* brow = fb + (size_t)i * FD_;
    __shared__ float red[2][4];
    float dacc = 0.f;  // accumulated by thread 0
    for (int p = 0; p < P_; p++) {
        float s2 = 0.f, sc = 0.f;
        int off = p * D_;
        for (int d = tid; d < D_; d += 256) {
            float f = frow[off + d];
            float c = crow[off + d];
            brow[off + d] = __float2bfloat16(f);
            s2 += f * f;
            float df = f - c;
            sc += df * df;
        }
        for (int o = 32; o; o >>= 1) {
            s2 += __shfl_down(s2, o, 64);
            sc += __shfl_down(sc, o, 64);
        }
        int wid = tid >> 6, lane = tid & 63;
        if (lane == 0) { red[0][wid] = s2; red[1][wid] = sc; }
        __syncthreads();
        if (tid == 0) {
            float t2 = red[0][0] + red[0][1] + red[0][2] + red[0][3];
            float tc = red[1][0] + red[1][1] + red[1][2] + red[1][3];
            sq[i * P_ + p] = t2;
            dacc += sqrtf(fmaxf(tc, EPS_));
        }
        __syncthreads();
    }
    if (tid == 0) dap[i] = dacc;
}

// ---------------- kernel 4: MFMA pair kernel ----------------
// grid (16,16,2): 64x64 (i,j) tile, z = p-half (p in [z*4, z*4+4))
// block 256 = 4 waves in 2x2, each wave a 32x32 subtile (2x2 of 16x16x32 MFMA)
// writes partial dist_aa (sum over 4 planes of sqrt) to pd[z][i][j]
__global__ __launch_bounds__(256) void k_pairs(const u16* __restrict__ fb,
                                               const float* __restrict__ sq,
                                               float* __restrict__ pd) {
    const int i0 = blockIdx.y * 64, j0 = blockIdx.x * 64;
    const int z = blockIdx.z;
    __shared__ u16 As[64 * 72];  // +8 bf16 pad -> 144B row stride, 2-way-conflict-free b128
    __shared__ u16 Bs[64 * 72];
    __shared__ float sqA[64 * 8], sqB[64 * 8];
    int tid = threadIdx.x;
    for (int t = tid; t < 512; t += 256) {
        int r = t >> 3, p = t & 7;
        sqA[t] = sq[(i0 + r) * 8 + p];
        sqB[t] = sq[(j0 + r) * 8 + p];
    }
    int lane = tid & 63, wid = tid >> 6;
    int wi = (wid >> 1) * 32, wj = (wid & 1) * 32;
    int lhi = lane >> 4, llo = lane & 15;
    // staging: thread t loads 32B (16 bf16) of row (t>>2), col (t&3)*16, per tile
    int srow = tid >> 2;
    int scol = (tid & 3) * 16;
    const u16* gA = fb + (size_t)(i0 + srow) * FD_ + scol;
    const u16* gB = fb + (size_t)(j0 + srow) * FD_ + scol;
    u16* lA = &As[srow * 72 + scol];
    u16* lB = &Bs[srow * 72 + scol];

    float4_t acc[2][2];
    float dacc[2][2][4];
#pragma unroll
    for (int a = 0; a < 2; a++)
#pragma unroll
        for (int b = 0; b < 2; b++)
#pragma unroll
            for (int r = 0; r < 4; r++) dacc[a][b][r] = 0.f;

    for (int pp = 0; pp < 4; pp++) {
        int p = z * 4 + pp;
#pragma unroll
        for (int a = 0; a < 2; a++)
#pragma unroll
            for (int b = 0; b < 2; b++) acc[a][b] = (float4_t){0.f, 0.f, 0.f, 0.f};
        for (int kb = 0; kb < D_ / 64; kb++) {
            size_t goff = (size_t)p * D_ + (size_t)kb * 64;
            __syncthreads();  // previous stage's reads done
            uint4 va0 = *(const uint4*)(gA + goff);
            uint4 va1 = *(const uint4*)(gA + goff + 8);
            uint4 vb0 = *(const uint4*)(gB + goff);
            uint4 vb1 = *(const uint4*)(gB + goff + 8);
            *(uint4*)lA = va0;
            *(uint4*)(lA + 8) = va1;
            *(uint4*)lB = vb0;
            *(uint4*)(lB + 8) = vb1;
            __syncthreads();
#pragma unroll
            for (int ks = 0; ks < 2; ks++) {
                int ko = ks * 32 + lhi * 8;
                short8_t af[2], bf2[2];
#pragma unroll
                for (int a = 0; a < 2; a++) {
                    af[a]  = *(const short8_t*)(&As[(wi + a * 16 + llo) * 72 + ko]);
                    bf2[a] = *(const short8_t*)(&Bs[(wj + a * 16 + llo) * 72 + ko]);
                }
#pragma unroll
                for (int a = 0; a < 2; a++)
#pragma unroll
                    for (int b = 0; b < 2; b++)
                        acc[a][b] = __builtin_amdgcn_mfma_f32_16x16x32_bf16(
                            af[a], bf2[b], acc[a][b], 0, 0, 0);
            }
        }
        // per-plane epilogue: d2 -> sqrt -> accumulate
        // C/D layout: col = lane&15, row = (lane>>4)*4 + reg
#pragma unroll
        for (int a = 0; a < 2; a++)
#pragma unroll
            for (int b = 0; b < 2; b++)
#pragma unroll
                for (int r = 0; r < 4; r++) {
                    int il = wi + a * 16 + lhi * 4 + r;
                    int jl = wj + b * 16 + llo;
                    float d2 = sqA[il * 8 + p] + sqB[jl * 8 + p] - 2.0f * acc[a][b][r];
                    dacc[a][b][r] += sqrtf(fmaxf(d2, EPS_));
                }
    }
    float* out = pd + (size_t)z * B_ * B_;
#pragma unroll
    for (int a = 0; a < 2; a++)
#pragma unroll
        for (int b = 0; b < 2; b++)
#pragma unroll
            for (int r = 0; r < 4; r++) {
                int il = wi + a * 16 + lhi * 4 + r;
                int jl = wj + b * 16 + llo;
                out[(size_t)(i0 + il) * B_ + (j0 + jl)] = dacc[a][b][r];
            }
}

// ---------------- kernel 5: masked margin reduction ----------------
// grid 1024 (one block per row i), block 256
__global__ void k_lossred(const float* __restrict__ pd, const float* __restrict__ dap,
                          const int* __restrict__ labels, float* possum) {
    int i = blockIdx.x;
    int tid = threadIdx.x;
    float di = dap[i];
    int li = labels[i];
    float lsum = 0.f;
    for (int j = tid; j < B_; j += 256) {
        if (labels[j] != li) {
            float daa = pd[(size_t)i * B_ + j] + pd[(size_t)B_ * B_ + (size_t)i * B_ + j];
            float v = di + dap[j] - daa + MARGIN_;
            lsum += fmaxf(v, 0.f);
        }
    }
    for (int o = 32; o; o >>= 1) lsum += __shfl_down(lsum, o, 64);
    __shared__ float red[4];
    int wid = tid >> 6, lane = tid & 63;
    if (lane == 0) red[wid] = lsum;
    __syncthreads();
    if (tid == 0) atomicAdd(possum, red[0] + red[1] + red[2] + red[3]);
}

__global__ void k_finalize(const float* possum, const float* negcnt, float* out) {
    out[0] = possum[0] / negcnt[0];
}

// ---------------- launch ----------------
extern "C" void kernel_launch(void* const* d_in, const int* in_sizes, int n_in,
                              void* d_out, int out_size, void* d_ws, size_t ws_size,
                              hipStream_t stream) {
    const float* feats = (const float*)d_in[0];
    const int* labels  = (const int*)d_in[1];
    // d_in[2] (subs) is unused by the reference
    float* out = (float*)d_out;

    char* w = (char*)d_ws;
    float* centers = (float*)(w + OFF_CENTERS);
    float* countsf = (float*)(w + OFF_COUNTS);
    float* negcnt  = (float*)(w + OFF_NEG);
    float* possum  = (float*)(w + OFF_POS);
    float* sq      = (float*)(w + OFF_SQ);
    float* dap     = (float*)(w + OFF_DAP);
    __hip_bfloat16* fb = (__hip_bfloat16*)(w + OFF_FB);
    float* pd      = (float*)(w + OFF_PD);

    hipMemsetAsync(w + OFF_POS, 0, 4, stream);

    k_counts<<<1, 64, 0, stream>>>(labels, countsf, negcnt);
    k_centers<<<256, 256, 0, stream>>>(feats, labels, countsf, centers);
    k_rowstats<<<B_, 256, 0, stream>>>(feats, labels, centers, fb, sq, dap);
    k_pairs<<<dim3(16, 16, 2), 256, 0, stream>>>((const u16*)fb, sq, pd);
    k_lossred<<<B_, 256, 0, stream>>>(pd, dap, labels, possum);
    k_finalize<<<1, 1, 0, stream>>>(possum, negcnt, out);
}

// Round 2
// 316.851 us; speedup vs baseline: 1.0391x; 1.0391x over previous
//
#include <hip/hip_runtime.h>
#include <hip/hip_bf16.h>

#define B_ 1024
#define P_ 8
#define D_ 2048
#define FD_ (P_ * D_)   // 16384
#define NID 64
#define MARGIN_ 0.3f
#define EPS_ 1e-12f

typedef unsigned short u16;
typedef short short8_t __attribute__((ext_vector_type(8)));
typedef float float4_t __attribute__((ext_vector_type(4)));

#define AS1 __attribute__((address_space(1)))
#define AS3 __attribute__((address_space(3)))

// ---------------- workspace layout (bytes) ----------------
static const size_t OFF_CENTERS = 0;                               // 64*16384*4 = 4,194,304
static const size_t OFF_COUNTS  = 4194304;                         // 64 fp32
static const size_t OFF_OFFS    = OFF_COUNTS + 256;                // 64 int
static const size_t OFF_PERM    = OFF_OFFS + 256;                  // 1024 int
static const size_t OFF_NEG     = OFF_PERM + 4096;
static const size_t OFF_POS     = OFF_NEG + 16;
static const size_t OFF_SQ      = OFF_POS + 16;                    // 1024*8 fp32
static const size_t OFF_DAP     = OFF_SQ + (size_t)B_ * P_ * 4;    // 1024 fp32
static const size_t OFF_FB      = OFF_DAP + (size_t)B_ * 4;        // 1024*16384 bf16 = 33,554,432
static const size_t OFF_PD      = OFF_FB + (size_t)B_ * FD_ * 2;   // 1024*1024 fp32 = 4,194,304
// total ~40.0 MB (< round-1's 46.2 MB which fit)

// ---------------- kernel 1: counts + prefix + per-class row lists + negcnt ----------------
__global__ void k_counts(const int* __restrict__ labels, float* countsf, int* offs,
                         int* perm, float* negcnt) {
    int c = threadIdx.x;  // 64 threads
    int cnt = 0;
    for (int i = 0; i < B_; i++) cnt += (labels[i] == c) ? 1 : 0;
    countsf[c] = (float)cnt;
    __shared__ int scnt[NID];
    scnt[c] = cnt;
    __syncthreads();
    int off = 0;
    for (int k = 0; k < c; k++) off += scnt[k];
    offs[c] = off;
    int w = off;
    for (int i = 0; i < B_; i++)
        if (labels[i] == c) perm[w++] = i;
    if (c == 0) {
        long long s = 0;
        for (int k = 0; k < NID; k++) s += (long long)scnt[k] * scnt[k];
        *negcnt = (float)((long long)B_ * B_ - s);
    }
}

// ---------------- kernel 2: segment-mean centers via row lists ----------------
// grid 512: cls = bid>>3, chunk = bid&7 (2048 dims); block 256; 8 floats/thread
__global__ void k_centers(const float* __restrict__ feats, const int* __restrict__ offs,
                          const int* __restrict__ perm, const float* __restrict__ countsf,
                          float* __restrict__ centers) {
    int cls = blockIdx.x >> 3;
    int ch  = blockIdx.x & 7;
    int base = ch * 2048 + threadIdx.x * 4;  // +0 and +1024
    float a0 = 0.f, a1 = 0.f, a2 = 0.f, a3 = 0.f;
    float b0 = 0.f, b1 = 0.f, b2 = 0.f, b3 = 0.f;
    int off = offs[cls];
    int cnt = (int)countsf[cls];
    for (int m = 0; m < cnt; m++) {
        const float* row = feats + (size_t)perm[off + m] * FD_ + base;
        float4 f0 = *(const float4*)(row);
        float4 f1 = *(const float4*)(row + 1024);
        a0 += f0.x; a1 += f0.y; a2 += f0.z; a3 += f0.w;
        b0 += f1.x; b1 += f1.y; b2 += f1.z; b3 += f1.w;
    }
    float inv = 1.0f / fmaxf((float)cnt, 1.0f);
    float* crow = centers + (size_t)cls * FD_ + base;
    float4 o0 = {a0 * inv, a1 * inv, a2 * inv, a3 * inv};
    float4 o1 = {b0 * inv, b1 * inv, b2 * inv, b3 * inv};
    *(float4*)(crow) = o0;
    *(float4*)(crow + 1024) = o1;
}

// ---------------- kernel 3: bf16 cast + sq + d_ap (wave-per-plane) ----------------
// grid 1024, block 256 (4 waves); wave w handles planes 2w, 2w+1
__global__ void k_rowstats(const float* __restrict__ feats, const int* __restrict__ labels,
                           const float* __restrict__ centers, __hip_bfloat16* __restrict__ fb,
                           float* __restrict__ sq, float* __restrict__ dap) {
    int i = blockIdx.x;
    int tid = threadIdx.x;
    int w = tid >> 6, lane = tid & 63;
    int lab = labels[i];
    const float* frow = feats + (size_t)i * FD_;
    const float* crow = centers + (size_t)lab * FD_;
    u16* brow = (u16*)(fb + (size_t)i * FD_);
    __shared__ float dsum[4];
    float dacc = 0.f;
#pragma unroll
    for (int pp = 0; pp < 2; pp++) {
        int p = w * 2 + pp;
        int off = p * D_;
        float s2 = 0.f, sc = 0.f;
#pragma unroll
        for (int ch = 0; ch < 8; ch++) {
            int d = off + ch * 256 + lane * 4;
            float4 f = *(const float4*)(frow + d);
            float4 c = *(const float4*)(crow + d);
            ushort4 b;
            b.x = __bfloat16_as_ushort(__float2bfloat16(f.x));
            b.y = __bfloat16_as_ushort(__float2bfloat16(f.y));
            b.z = __bfloat16_as_ushort(__float2bfloat16(f.z));
            b.w = __bfloat16_as_ushort(__float2bfloat16(f.w));
            *(ushort4*)(brow + d) = b;
            s2 += f.x * f.x + f.y * f.y + f.z * f.z + f.w * f.w;
            float dx = f.x - c.x, dy = f.y - c.y, dz = f.z - c.z, dw = f.w - c.w;
            sc += dx * dx + dy * dy + dz * dz + dw * dw;
        }
        for (int o = 32; o; o >>= 1) {
            s2 += __shfl_down(s2, o, 64);
            sc += __shfl_down(sc, o, 64);
        }
        if (lane == 0) {
            sq[i * P_ + p] = s2;
            dacc += sqrtf(fmaxf(sc, EPS_));
        }
    }
    if (lane == 0) dsum[w] = dacc;
    __syncthreads();
    if (tid == 0) dap[i] = dsum[0] + dsum[1] + dsum[2] + dsum[3];
}

// ---------------- kernel 4: MFMA pair kernel, m97-style ----------------
// grid (8,8,8): 128x128 (i,j) tile, z = plane p. block 256 = 4 waves (2x2),
// wave tile 64x64 = 4x4 of 16x16x32. global_load_lds staging with XOR chunk
// swizzle (chunk = 16B = 8 bf16; physical chunk = logical ^ (row&7)).
// Epilogue: sqrt(d2) atomicAdd into single B x B plane pd.
__global__ __launch_bounds__(256) void k_pairs(const u16* __restrict__ fb,
                                               const float* __restrict__ sq,
                                               float* __restrict__ pd) {
    const int i0 = blockIdx.y * 128, j0 = blockIdx.x * 128;
    const int p = blockIdx.z;
    __shared__ u16 As[128 * 64];
    __shared__ u16 Bs[128 * 64];
    __shared__ float sqAs[128], sqBs[128];
    const int tid = threadIdx.x;
    const int lane = tid & 63, wid = tid >> 6;
    if (tid < 128) sqAs[tid] = sq[(i0 + tid) * 8 + p];
    else           sqBs[tid - 128] = sq[(j0 + tid - 128) * 8 + p];

    const int wi = (wid >> 1) * 64, wj = (wid & 1) * 64;
    const int lhi = lane >> 4, llo = lane & 15;
    const int sl = llo & 7;  // row&7 for fragment reads

    // staging lane geometry: 1 instr = 8 rows x 64 elems; lane L -> row base+ (L>>3),
    // physical chunk L&7, which must hold logical chunk (L&7)^(L>>3)
    const int lr = lane >> 3;
    const int lc = (lane & 7) ^ lr;
    const u16* gA[4];
    const u16* gB[4];
    u16* lA[4];
    u16* lB[4];
#pragma unroll
    for (int inst = 0; inst < 4; inst++) {
        int r0 = wid * 32 + inst * 8;
        gA[inst] = fb + (size_t)(i0 + r0 + lr) * FD_ + (size_t)p * D_ + lc * 8;
        gB[inst] = fb + (size_t)(j0 + r0 + lr) * FD_ + (size_t)p * D_ + lc * 8;
        lA[inst] = &As[r0 * 64];  // wave-uniform; HW adds lane*16B
        lB[inst] = &Bs[r0 * 64];
    }

    float4_t acc[4][4];
#pragma unroll
    for (int a = 0; a < 4; a++)
#pragma unroll
        for (int b = 0; b < 4; b++) acc[a][b] = (float4_t){0.f, 0.f, 0.f, 0.f};

    for (int kb = 0; kb < D_ / 64; kb++) {
        const int koff = kb * 64;
        __syncthreads();  // previous stage's LDS reads done
#pragma unroll
        for (int inst = 0; inst < 4; inst++) {
            __builtin_amdgcn_global_load_lds((const AS1 void*)(gA[inst] + koff),
                                             (AS3 void*)lA[inst], 16, 0, 0);
            __builtin_amdgcn_global_load_lds((const AS1 void*)(gB[inst] + koff),
                                             (AS3 void*)lB[inst], 16, 0, 0);
        }
        __syncthreads();  // staging complete (compiler drains vmcnt before barrier)
#pragma unroll
        for (int ks = 0; ks < 2; ks++) {
            const int pc = ((ks * 4 + lhi) ^ sl) * 8;
            short8_t af[4], bf[4];
#pragma unroll
            for (int a = 0; a < 4; a++) {
                af[a] = *(const short8_t*)(&As[(wi + a * 16 + llo) * 64 + pc]);
                bf[a] = *(const short8_t*)(&Bs[(wj + a * 16 + llo) * 64 + pc]);
            }
#pragma unroll
            for (int a = 0; a < 4; a++)
#pragma unroll
                for (int b = 0; b < 4; b++)
                    acc[a][b] = __builtin_amdgcn_mfma_f32_16x16x32_bf16(
                        af[a], bf[b], acc[a][b], 0, 0, 0);
        }
    }
    // epilogue: d2 -> sqrt -> atomic accumulate into pd
    // C/D layout: col = lane&15, row = (lane>>4)*4 + reg
#pragma unroll
    for (int a = 0; a < 4; a++)
#pragma unroll
        for (int b = 0; b < 4; b++)
#pragma unroll
            for (int r = 0; r < 4; r++) {
                int il = wi + a * 16 + lhi * 4 + r;
                int jl = wj + b * 16 + llo;
                float d2 = sqAs[il] + sqBs[jl] - 2.0f * acc[a][b][r];
                atomicAdd(&pd[(size_t)(i0 + il) * B_ + (j0 + jl)],
                          sqrtf(fmaxf(d2, EPS_)));
            }
}

// ---------------- kernel 5: masked margin reduction ----------------
__global__ void k_lossred(const float* __restrict__ pd, const float* __restrict__ dap,
                          const int* __restrict__ labels, float* possum) {
    int i = blockIdx.x;
    int tid = threadIdx.x;
    float di = dap[i];
    int li = labels[i];
    float lsum = 0.f;
    for (int j = tid; j < B_; j += 256) {
        if (labels[j] != li) {
            float v = di + dap[j] - pd[(size_t)i * B_ + j] + MARGIN_;
            lsum += fmaxf(v, 0.f);
        }
    }
    for (int o = 32; o; o >>= 1) lsum += __shfl_down(lsum, o, 64);
    __shared__ float red[4];
    int wid = tid >> 6, lane = tid & 63;
    if (lane == 0) red[wid] = lsum;
    __syncthreads();
    if (tid == 0) atomicAdd(possum, red[0] + red[1] + red[2] + red[3]);
}

__global__ void k_finalize(const float* possum, const float* negcnt, float* out) {
    out[0] = possum[0] / negcnt[0];
}

// ---------------- launch ----------------
extern "C" void kernel_launch(void* const* d_in, const int* in_sizes, int n_in,
                              void* d_out, int out_size, void* d_ws, size_t ws_size,
                              hipStream_t stream) {
    const float* feats = (const float*)d_in[0];
    const int* labels  = (const int*)d_in[1];
    float* out = (float*)d_out;

    char* w = (char*)d_ws;
    float* centers = (float*)(w + OFF_CENTERS);
    float* countsf = (float*)(w + OFF_COUNTS);
    int* offs      = (int*)(w + OFF_OFFS);
    int* perm      = (int*)(w + OFF_PERM);
    float* negcnt  = (float*)(w + OFF_NEG);
    float* possum  = (float*)(w + OFF_POS);
    float* sq      = (float*)(w + OFF_SQ);
    float* dap     = (float*)(w + OFF_DAP);
    __hip_bfloat16* fb = (__hip_bfloat16*)(w + OFF_FB);
    float* pd      = (float*)(w + OFF_PD);

    hipMemsetAsync(w + OFF_POS, 0, 4, stream);
    hipMemsetAsync(pd, 0, (size_t)B_ * B_ * 4, stream);

    k_counts<<<1, 64, 0, stream>>>(labels, countsf, offs, perm, negcnt);
    k_centers<<<512, 256, 0, stream>>>(feats, offs, perm, countsf, centers);
    k_rowstats<<<B_, 256, 0, stream>>>(feats, labels, centers, fb, sq, dap);
    k_pairs<<<dim3(8, 8, 8), 256, 0, stream>>>((const u16*)fb, sq, pd);
    k_lossred<<<B_, 256, 0, stream>>>(pd, dap, labels, possum);
    k_finalize<<<1, 1, 0, stream>>>(possum, negcnt, out);
}

// Round 3
// 193.290 us; speedup vs baseline: 1.7033x; 1.6392x over previous
//
#include <hip/hip_runtime.h>
#include <hip/hip_bf16.h>

#define B_ 1024
#define P_ 8
#define D_ 2048
#define FD_ (P_ * D_)   // 16384
#define NID 64
#define MARGIN_ 0.3f
#define EPS_ 1e-12f

typedef unsigned short u16;
typedef short short8_t __attribute__((ext_vector_type(8)));
typedef float float4_t __attribute__((ext_vector_type(4)));

#define AS1 __attribute__((address_space(1)))
#define AS3 __attribute__((address_space(3)))

__device__ __forceinline__ float bf2f(u16 v) {
    unsigned x = (unsigned)v << 16;
    float f;
    __builtin_memcpy(&f, &x, 4);
    return f;
}

// ---------------- workspace layout (bytes) ----------------
static const size_t OFF_COUNTS  = 0;        // 64 fp32
static const size_t OFF_OFFS    = 256;      // 64 int
static const size_t OFF_PERM    = 512;      // 1024 int
static const size_t OFF_NEG     = 4608;
static const size_t OFF_POS     = 4624;
static const size_t OFF_SQ      = 65536;    // 1024*8 fp32 = 32 KB
static const size_t OFF_DAP     = 98304;    // 1024 fp32
static const size_t OFF_CENTERS = 131072;   // 64*16384 fp32 = 4 MB
static const size_t OFF_FB      = OFF_CENTERS + 4194304;          // 32 MB bf16
static const size_t OFF_PD      = OFF_FB + (size_t)B_ * FD_ * 2;  // 8 planes * 1024*1024 bf16 = 16 MB
// total = 131072 + 4 MB + 32 MB + 16 MB ≈ 52.2 MB... reduce: overlay centers under pd?
// centers dead before k_pairs writes pd, but they'd collide with fb ordering.
// Keep linear: 52.2 MB total.

// ---------------- kernel 1: histogram counts + prefix + perm + negcnt ----------------
__global__ void k_counts(const int* __restrict__ labels, float* countsf, int* offs,
                         int* perm, float* negcnt) {
    __shared__ int h[NID], o[NID], cur[NID];
    int tid = threadIdx.x;
    if (tid < NID) h[tid] = 0;
    __syncthreads();
    for (int i = tid; i < B_; i += 256) atomicAdd(&h[labels[i]], 1);
    __syncthreads();
    if (tid == 0) {
        int acc = 0;
        long long ss = 0;
        for (int c = 0; c < NID; c++) {
            o[c] = acc;
            acc += h[c];
            ss += (long long)h[c] * h[c];
        }
        *negcnt = (float)((long long)B_ * B_ - ss);
    }
    __syncthreads();
    if (tid < NID) {
        countsf[tid] = (float)h[tid];
        offs[tid] = o[tid];
        cur[tid] = o[tid];
    }
    __syncthreads();
    for (int i = tid; i < B_; i += 256) {
        int pos = atomicAdd(&cur[labels[i]], 1);
        perm[pos] = i;
    }
}

// ---------------- kernel 2: segment-mean centers via row lists ----------------
// grid 512: cls = bid>>3, chunk = bid&7 (2048 dims); block 256; 8 floats/thread
__global__ void k_centers(const float* __restrict__ feats, const int* __restrict__ offs,
                          const int* __restrict__ perm, const float* __restrict__ countsf,
                          float* __restrict__ centers) {
    int cls = blockIdx.x >> 3;
    int ch  = blockIdx.x & 7;
    int base = ch * 2048 + threadIdx.x * 4;  // +0 and +1024
    float a0 = 0.f, a1 = 0.f, a2 = 0.f, a3 = 0.f;
    float b0 = 0.f, b1 = 0.f, b2 = 0.f, b3 = 0.f;
    int off = offs[cls];
    int cnt = (int)countsf[cls];
    for (int m = 0; m < cnt; m++) {
        const float* row = feats + (size_t)perm[off + m] * FD_ + base;
        float4 f0 = *(const float4*)(row);
        float4 f1 = *(const float4*)(row + 1024);
        a0 += f0.x; a1 += f0.y; a2 += f0.z; a3 += f0.w;
        b0 += f1.x; b1 += f1.y; b2 += f1.z; b3 += f1.w;
    }
    float inv = 1.0f / fmaxf((float)cnt, 1.0f);
    float* crow = centers + (size_t)cls * FD_ + base;
    float4 o0 = {a0 * inv, a1 * inv, a2 * inv, a3 * inv};
    float4 o1 = {b0 * inv, b1 * inv, b2 * inv, b3 * inv};
    *(float4*)(crow) = o0;
    *(float4*)(crow + 1024) = o1;
}

// ---------------- kernel 3: bf16 cast + sq + d_ap (wave-per-plane-pair) ----------------
__global__ void k_rowstats(const float* __restrict__ feats, const int* __restrict__ labels,
                           const float* __restrict__ centers, __hip_bfloat16* __restrict__ fb,
                           float* __restrict__ sq, float* __restrict__ dap) {
    int i = blockIdx.x;
    int tid = threadIdx.x;
    int w = tid >> 6, lane = tid & 63;
    int lab = labels[i];
    const float* frow = feats + (size_t)i * FD_;
    const float* crow = centers + (size_t)lab * FD_;
    u16* brow = (u16*)(fb + (size_t)i * FD_);
    __shared__ float dsum[4];
    float dacc = 0.f;
#pragma unroll
    for (int pp = 0; pp < 2; pp++) {
        int p = w * 2 + pp;
        int off = p * D_;
        float s2 = 0.f, sc = 0.f;
#pragma unroll
        for (int ch = 0; ch < 8; ch++) {
            int d = off + ch * 256 + lane * 4;
            float4 f = *(const float4*)(frow + d);
            float4 c = *(const float4*)(crow + d);
            ushort4 b;
            b.x = __bfloat16_as_ushort(__float2bfloat16(f.x));
            b.y = __bfloat16_as_ushort(__float2bfloat16(f.y));
            b.z = __bfloat16_as_ushort(__float2bfloat16(f.z));
            b.w = __bfloat16_as_ushort(__float2bfloat16(f.w));
            *(ushort4*)(brow + d) = b;
            s2 += f.x * f.x + f.y * f.y + f.z * f.z + f.w * f.w;
            float dx = f.x - c.x, dy = f.y - c.y, dz = f.z - c.z, dw = f.w - c.w;
            sc += dx * dx + dy * dy + dz * dz + dw * dw;
        }
        for (int o = 32; o; o >>= 1) {
            s2 += __shfl_down(s2, o, 64);
            sc += __shfl_down(sc, o, 64);
        }
        if (lane == 0) {
            sq[i * P_ + p] = s2;
            dacc += sqrtf(fmaxf(sc, EPS_));
        }
    }
    if (lane == 0) dsum[w] = dacc;
    __syncthreads();
    if (tid == 0) dap[i] = dsum[0] + dsum[1] + dsum[2] + dsum[3];
}

// ---------------- kernel 4: MFMA pair kernel, 8 waves = 4 spatial x 2 K-halves ----
// grid (8,8,8): 128x128 (i,j) tile, z = plane p. block 512.
// Wave (h,s): spatial 64x64 subtile s, K range [h*1024, h*1024+1024).
// Staging per half into its own 32 KB LDS region via global_load_lds w/ XOR swizzle.
// Epilogue: h=1 accs -> LDS, h=0 combines, sqrt(d2), bf16 store to pd[p] plane.
__global__ __launch_bounds__(512, 4) void k_pairs(const u16* __restrict__ fb,
                                                  const float* __restrict__ sq,
                                                  u16* __restrict__ pd) {
    const int i0 = blockIdx.y * 128, j0 = blockIdx.x * 128;
    const int p = blockIdx.z;
    // smem: As[h] = [h*8192, h*8192+8192), Bs[h] = [16384+h*8192, ...): 64 KB total
    __shared__ u16 smem[32768];
    __shared__ float sqAs[128], sqBs[128];
    const int tid = threadIdx.x;
    const int lane = tid & 63, wid = tid >> 6;
    const int s = wid & 3, h = wid >> 2;
    if (tid < 128) sqAs[tid] = sq[(i0 + tid) * 8 + p];
    else if (tid < 256) sqBs[tid - 128] = sq[(j0 + tid - 128) * 8 + p];

    const int wi = (s >> 1) * 64, wj = (s & 1) * 64;
    const int lhi = lane >> 4, llo = lane & 15;
    const int sl = llo & 7;
    // staging geometry: lane L -> row (L>>3), physical chunk L&7 holds logical (L&7)^(L>>3)
    const int lr = lane >> 3;
    const int lc = (lane & 7) ^ lr;

    u16* const As = &smem[h * 8192];
    u16* const Bs = &smem[16384 + h * 8192];

    const size_t colbase = (size_t)p * D_ + (size_t)h * 1024 + (size_t)lc * 8;
    const u16* gA[4];
    const u16* gB[4];
    u16* lA[4];
    u16* lB[4];
#pragma unroll
    for (int inst = 0; inst < 4; inst++) {
        int r0 = s * 32 + inst * 8;
        gA[inst] = fb + (size_t)(i0 + r0 + lr) * FD_ + colbase;
        gB[inst] = fb + (size_t)(j0 + r0 + lr) * FD_ + colbase;
        lA[inst] = As + r0 * 64;  // wave-uniform base; HW adds lane*16B
        lB[inst] = Bs + r0 * 64;
    }

    float4_t acc[4][4];
#pragma unroll
    for (int a = 0; a < 4; a++)
#pragma unroll
        for (int b = 0; b < 4; b++) acc[a][b] = (float4_t){0.f, 0.f, 0.f, 0.f};

    for (int kb = 0; kb < 16; kb++) {
        const int koff = kb * 64;
        __syncthreads();
#pragma unroll
        for (int inst = 0; inst < 4; inst++) {
            __builtin_amdgcn_global_load_lds((const AS1 void*)(gA[inst] + koff),
                                             (AS3 void*)lA[inst], 16, 0, 0);
            __builtin_amdgcn_global_load_lds((const AS1 void*)(gB[inst] + koff),
                                             (AS3 void*)lB[inst], 16, 0, 0);
        }
        __syncthreads();
#pragma unroll
        for (int ks = 0; ks < 2; ks++) {
            const int pc = ((ks * 4 + lhi) ^ sl) * 8;
            short8_t af[4], bf[4];
#pragma unroll
            for (int a = 0; a < 4; a++) {
                af[a] = *(const short8_t*)(&As[(wi + a * 16 + llo) * 64 + pc]);
                bf[a] = *(const short8_t*)(&Bs[(wj + a * 16 + llo) * 64 + pc]);
            }
#pragma unroll
            for (int a = 0; a < 4; a++)
#pragma unroll
                for (int b = 0; b < 4; b++)
                    acc[a][b] = __builtin_amdgcn_mfma_f32_16x16x32_bf16(
                        af[a], bf[b], acc[a][b], 0, 0, 0);
        }
    }
    // ---- epilogue: combine K-halves through LDS, sqrt, store bf16 ----
    __syncthreads();  // all ds_reads of smem done before reuse
    float* ep = (float*)smem;  // 16384 floats = 64 KB
    if (h == 1) {
#pragma unroll
        for (int a = 0; a < 4; a++)
#pragma unroll
            for (int b = 0; b < 4; b++)
                *(float4_t*)&ep[(((s * 4 + a) * 4 + b) * 64 + lane) * 4] = acc[a][b];
    }
    __syncthreads();
    if (h == 0) {
        u16* outp = pd + (size_t)p * B_ * B_;
#pragma unroll
        for (int a = 0; a < 4; a++)
#pragma unroll
            for (int b = 0; b < 4; b++) {
                float4_t o = *(const float4_t*)&ep[(((s * 4 + a) * 4 + b) * 64 + lane) * 4];
#pragma unroll
                for (int r = 0; r < 4; r++) {
                    int il = wi + a * 16 + lhi * 4 + r;
                    int jl = wj + b * 16 + llo;
                    float t = acc[a][b][r] + o[r];
                    float d2 = sqAs[il] + sqBs[jl] - 2.0f * t;
                    float v = sqrtf(fmaxf(d2, EPS_));
                    outp[(size_t)(i0 + il) * B_ + (j0 + jl)] =
                        __bfloat16_as_ushort(__float2bfloat16(v));
                }
            }
    }
}

// ---------------- kernel 5: masked margin reduction over 8 bf16 planes ----------------
__global__ void k_lossred(const u16* __restrict__ pd, const float* __restrict__ dap,
                          const int* __restrict__ labels, float* possum) {
    int i = blockIdx.x;
    int tid = threadIdx.x;
    float di = dap[i];
    int li = labels[i];
    float lsum = 0.f;
    for (int j = tid; j < B_; j += 256) {
        if (labels[j] != li) {
            float daa = 0.f;
#pragma unroll
            for (int p = 0; p < P_; p++)
                daa += bf2f(pd[(size_t)p * B_ * B_ + (size_t)i * B_ + j]);
            float v = di + dap[j] - daa + MARGIN_;
            lsum += fmaxf(v, 0.f);
        }
    }
    for (int o = 32; o; o >>= 1) lsum += __shfl_down(lsum, o, 64);
    __shared__ float red[4];
    int wid = tid >> 6, lane = tid & 63;
    if (lane == 0) red[wid] = lsum;
    __syncthreads();
    if (tid == 0) atomicAdd(possum, red[0] + red[1] + red[2] + red[3]);
}

__global__ void k_finalize(const float* possum, const float* negcnt, float* out) {
    out[0] = possum[0] / negcnt[0];
}

// ---------------- launch ----------------
extern "C" void kernel_launch(void* const* d_in, const int* in_sizes, int n_in,
                              void* d_out, int out_size, void* d_ws, size_t ws_size,
                              hipStream_t stream) {
    const float* feats = (const float*)d_in[0];
    const int* labels  = (const int*)d_in[1];
    float* out = (float*)d_out;

    char* w = (char*)d_ws;
    float* countsf = (float*)(w + OFF_COUNTS);
    int* offs      = (int*)(w + OFF_OFFS);
    int* perm      = (int*)(w + OFF_PERM);
    float* negcnt  = (float*)(w + OFF_NEG);
    float* possum  = (float*)(w + OFF_POS);
    float* sq      = (float*)(w + OFF_SQ);
    float* dap     = (float*)(w + OFF_DAP);
    float* centers = (float*)(w + OFF_CENTERS);
    __hip_bfloat16* fb = (__hip_bfloat16*)(w + OFF_FB);
    u16* pd        = (u16*)(w + OFF_PD);

    hipMemsetAsync(w + OFF_POS, 0, 4, stream);

    k_counts<<<1, 256, 0, stream>>>(labels, countsf, offs, perm, negcnt);
    k_centers<<<512, 256, 0, stream>>>(feats, offs, perm, countsf, centers);
    k_rowstats<<<B_, 256, 0, stream>>>(feats, labels, centers, fb, sq, dap);
    k_pairs<<<dim3(8, 8, 8), 512, 0, stream>>>((const u16*)fb, sq, pd);
    k_lossred<<<B_, 256, 0, stream>>>(pd, dap, labels, possum);
    k_finalize<<<1, 1, 0, stream>>>(possum, negcnt, out);
}

// Round 4
// 169.550 us; speedup vs baseline: 1.9418x; 1.1400x over previous
//
#include <hip/hip_runtime.h>
#include <hip/hip_bf16.h>

#define B_ 1024
#define P_ 8
#define D_ 2048
#define FD_ (P_ * D_)   // 16384
#define NID 64
#define MARGIN_ 0.3f
#define EPS_ 1e-12f

typedef unsigned short u16;
typedef float float4_t __attribute__((ext_vector_type(4)));

#define AS1 __attribute__((address_space(1)))
#define AS3 __attribute__((address_space(3)))

__device__ __forceinline__ float bf2f(u16 v) {
    unsigned x = (unsigned)v << 16;
    float f;
    __builtin_memcpy(&f, &x, 4);
    return f;
}

// ---------------- workspace layout (bytes) ----------------
static const size_t OFF_COUNTS = 0;         // 64 fp32
static const size_t OFF_OFFS   = 256;       // 64 int
static const size_t OFF_PERM   = 512;       // 1024 int -> ends 4608
static const size_t OFF_NEG    = 4608;
static const size_t OFF_POS    = 8176;      // adjacent to S so one memset covers both
static const size_t OFF_S      = 8192;      // 1024*8 fp32 = 32 KB -> 40960
static const size_t OFF_SQ     = 40960;     // 1024*8 fp32 = 32 KB -> 73728
static const size_t OFF_DAP    = 73728;     // 1024 fp32 -> 77824
static const size_t OFF_FB     = 131072;    // 1024*16384 fp8 = 16 MB
static const size_t OFF_PD     = OFF_FB + (size_t)B_ * FD_;  // 8 planes * 1024*1024 bf16 = 16 MB
// total ~33.7 MB

// ---------------- kernel 1: histogram counts + prefix + perm + negcnt ----------------
__global__ void k_counts(const int* __restrict__ labels, float* countsf, int* offs,
                         int* perm, float* negcnt) {
    __shared__ int h[NID], o[NID], cur[NID];
    int tid = threadIdx.x;
    if (tid < NID) h[tid] = 0;
    __syncthreads();
    for (int i = tid; i < B_; i += 256) atomicAdd(&h[labels[i]], 1);
    __syncthreads();
    if (tid == 0) {
        int acc = 0;
        long long ss = 0;
        for (int c = 0; c < NID; c++) {
            o[c] = acc;
            acc += h[c];
            ss += (long long)h[c] * h[c];
        }
        *negcnt = (float)((long long)B_ * B_ - ss);
    }
    __syncthreads();
    if (tid < NID) {
        countsf[tid] = (float)h[tid];
        offs[tid] = o[tid];
        cur[tid] = o[tid];
    }
    __syncthreads();
    for (int i = tid; i < B_; i += 256) {
        int pos = atomicAdd(&cur[labels[i]], 1);
        perm[pos] = i;
    }
}

// ---------------- kernel 2: fp8 cast + sq (wave-per-plane-pair) ----------------
__global__ void k_rowstats(const float* __restrict__ feats, unsigned char* __restrict__ fb,
                           float* __restrict__ sq) {
    int i = blockIdx.x;
    int tid = threadIdx.x;
    int w = tid >> 6, lane = tid & 63;
    const float* frow = feats + (size_t)i * FD_;
    unsigned char* brow = fb + (size_t)i * FD_;
#pragma unroll
    for (int pp = 0; pp < 2; pp++) {
        int p = w * 2 + pp;
        int off = p * D_;
        float s2 = 0.f;
#pragma unroll
        for (int ch = 0; ch < 8; ch++) {
            int d = off + ch * 256 + lane * 4;
            float4 f = *(const float4*)(frow + d);
            int pk = __builtin_amdgcn_cvt_pk_fp8_f32(f.x, f.y, 0, false);
            pk = __builtin_amdgcn_cvt_pk_fp8_f32(f.z, f.w, pk, true);
            *(unsigned int*)(brow + d) = (unsigned int)pk;
            s2 += f.x * f.x + f.y * f.y + f.z * f.z + f.w * f.w;
        }
        for (int o = 32; o; o >>= 1) s2 += __shfl_down(s2, o, 64);
        if (lane == 0) sq[i * P_ + p] = s2;
    }
}

// ---------------- kernel 3: fp8 MFMA pair kernel ----------------
// grid (8,8,8): 128x128 (i,j) tile, z = plane p. block 512 = 4 spatial x 2 K-half waves.
// K window per iter = 128 B (fp8), 8 iters per half. XOR chunk swizzle (16-B chunks,
// physical = logical ^ (row&7)) — byte-identical staging geometry to the validated
// round-3 kernel. Frags: ds_read_b64, 4 K-steps of 32, 64 MFMA per barrier pair.
// Epilogue: combine K-halves via LDS, sqrt -> bf16 pd; label-masked row sums -> S.
__global__ __launch_bounds__(512, 4) void k_pairs(const unsigned char* __restrict__ fb,
                                                  const float* __restrict__ sq,
                                                  const int* __restrict__ labels,
                                                  float* __restrict__ S,
                                                  u16* __restrict__ pd) {
    const int i0 = blockIdx.y * 128, j0 = blockIdx.x * 128;
    const int p = blockIdx.z;
    __shared__ __align__(16) unsigned char smem[65536];  // As[h]:[h*16K), Bs[h]:[32K+h*16K)
    __shared__ float sqAs[128], sqBs[128];
    __shared__ int labA[128], labB[128];
    const int tid = threadIdx.x;
    const int lane = tid & 63, wid = tid >> 6;
    const int s = wid & 3, h = wid >> 2;
    if (tid < 128) {
        sqAs[tid] = sq[(i0 + tid) * 8 + p];
        labA[tid] = labels[i0 + tid];
    } else if (tid < 256) {
        int t = tid - 128;
        sqBs[t] = sq[(j0 + t) * 8 + p];
        labB[t] = labels[j0 + t];
    }

    const int wi = (s >> 1) * 64, wj = (s & 1) * 64;
    const int lhi = lane >> 4, llo = lane & 15;
    const int sl = llo & 7;
    const int lr = lane >> 3;
    const int lc = (lane & 7) ^ lr;

    unsigned char* const As = smem + h * 16384;
    unsigned char* const Bs = smem + 32768 + h * 16384;

    const size_t colbase = (size_t)p * D_ + (size_t)h * 1024 + (size_t)lc * 16;
    const unsigned char* gA[4];
    const unsigned char* gB[4];
    unsigned char* lA[4];
    unsigned char* lB[4];
#pragma unroll
    for (int inst = 0; inst < 4; inst++) {
        int r0 = s * 32 + inst * 8;
        gA[inst] = fb + (size_t)(i0 + r0 + lr) * FD_ + colbase;
        gB[inst] = fb + (size_t)(j0 + r0 + lr) * FD_ + colbase;
        lA[inst] = As + r0 * 128;  // wave-uniform base; HW adds lane*16B
        lB[inst] = Bs + r0 * 128;
    }

    float4_t acc[4][4];
#pragma unroll
    for (int a = 0; a < 4; a++)
#pragma unroll
        for (int b = 0; b < 4; b++) acc[a][b] = (float4_t){0.f, 0.f, 0.f, 0.f};

    for (int kb = 0; kb < 8; kb++) {
        const int koff = kb * 128;
        __syncthreads();
#pragma unroll
        for (int inst = 0; inst < 4; inst++) {
            __builtin_amdgcn_global_load_lds((const AS1 void*)(gA[inst] + koff),
                                             (AS3 void*)lA[inst], 16, 0, 0);
            __builtin_amdgcn_global_load_lds((const AS1 void*)(gB[inst] + koff),
                                             (AS3 void*)lB[inst], 16, 0, 0);
        }
        __syncthreads();
#pragma unroll
        for (int ks = 0; ks < 4; ks++) {
            // lane quad lhi needs bytes [ks*32 + lhi*8, +8): logical chunk 2ks+(lhi>>1),
            // sub-offset (lhi&1)*8; physical chunk = logical ^ (row&7)
            const int pcb = ((2 * ks + (lhi >> 1)) ^ sl) * 16 + (lhi & 1) * 8;
            long af[4], bf[4];
#pragma unroll
            for (int a = 0; a < 4; a++) {
                af[a] = *(const long*)(As + (wi + a * 16 + llo) * 128 + pcb);
                bf[a] = *(const long*)(Bs + (wj + a * 16 + llo) * 128 + pcb);
            }
#pragma unroll
            for (int a = 0; a < 4; a++)
#pragma unroll
                for (int b = 0; b < 4; b++)
                    acc[a][b] = __builtin_amdgcn_mfma_f32_16x16x32_fp8_fp8(
                        af[a], bf[b], acc[a][b], 0, 0, 0);
        }
    }
    // ---- epilogue: combine K-halves, sqrt -> pd, masked row sums -> S ----
    __syncthreads();  // all ds_reads of smem done before reuse
    float* ep = (float*)smem;
    if (h == 1) {
#pragma unroll
        for (int a = 0; a < 4; a++)
#pragma unroll
            for (int b = 0; b < 4; b++)
                *(float4_t*)&ep[(((s * 4 + a) * 4 + b) * 64 + lane) * 4] = acc[a][b];
    }
    __syncthreads();
    if (h == 0) {
        u16* outp = pd + (size_t)p * B_ * B_;
        float rs[4][4];
#pragma unroll
        for (int a = 0; a < 4; a++)
#pragma unroll
            for (int r = 0; r < 4; r++) rs[a][r] = 0.f;
#pragma unroll
        for (int a = 0; a < 4; a++) {
            int la0 = labA[wi + a * 16 + lhi * 4 + 0];
            int la1 = labA[wi + a * 16 + lhi * 4 + 1];
            int la2 = labA[wi + a * 16 + lhi * 4 + 2];
            int la3 = labA[wi + a * 16 + lhi * 4 + 3];
#pragma unroll
            for (int b = 0; b < 4; b++) {
                float4_t o = *(const float4_t*)&ep[(((s * 4 + a) * 4 + b) * 64 + lane) * 4];
                int lb = labB[wj + b * 16 + llo];
                int jl = wj + b * 16 + llo;
#pragma unroll
                for (int r = 0; r < 4; r++) {
                    int il = wi + a * 16 + lhi * 4 + r;
                    float t = acc[a][b][r] + o[r];
                    float d2 = sqAs[il] + sqBs[jl] - 2.0f * t;
                    outp[(size_t)(i0 + il) * B_ + (j0 + jl)] =
                        __bfloat16_as_ushort(__float2bfloat16(sqrtf(fmaxf(d2, EPS_))));
                    int la = (r == 0) ? la0 : (r == 1) ? la1 : (r == 2) ? la2 : la3;
                    if (lb == la) rs[a][r] += t;
                }
            }
        }
#pragma unroll
        for (int a = 0; a < 4; a++)
#pragma unroll
            for (int r = 0; r < 4; r++) {
                float v = rs[a][r];
                v += __shfl_xor(v, 1, 64);
                v += __shfl_xor(v, 2, 64);
                v += __shfl_xor(v, 4, 64);
                v += __shfl_xor(v, 8, 64);
                if (llo == 0)
                    atomicAdd(&S[(size_t)(i0 + wi + a * 16 + lhi * 4 + r) * 8 + p], v);
            }
    }
}

// ---------------- kernel 4: d_ap from Gram row sums ----------------
// grid 64 (one class), block 64
__global__ void k_dap(const float* __restrict__ S, const float* __restrict__ sq,
                      const float* __restrict__ countsf, const int* __restrict__ offs,
                      const int* __restrict__ perm, float* __restrict__ dap) {
    int c = blockIdx.x;
    int tid = threadIdx.x;
    int cnt = (int)countsf[c];
    int off = offs[c];
    __shared__ float T[8];
    if (tid < 8) {
        float t = 0.f;
        for (int m = 0; m < cnt; m++) t += S[(size_t)perm[off + m] * 8 + tid];
        T[tid] = t;
    }
    __syncthreads();
    float n = fmaxf((float)cnt, 1.f);
    float inv = 1.f / n, inv2 = inv * inv;
    for (int m = tid; m < cnt; m += 64) {
        int i = perm[off + m];
        float d = 0.f;
#pragma unroll
        for (int p = 0; p < 8; p++) {
            float d2 = sq[i * 8 + p] - 2.f * inv * S[(size_t)i * 8 + p] + inv2 * T[p];
            d += sqrtf(fmaxf(d2, EPS_));
        }
        dap[i] = d;
    }
}

// ---------------- kernel 5: masked margin reduction over 8 bf16 planes ----------------
__global__ void k_lossred(const u16* __restrict__ pd, const float* __restrict__ dap,
                          const int* __restrict__ labels, float* possum) {
    int i = blockIdx.x;
    int tid = threadIdx.x;
    float di = dap[i];
    int li = labels[i];
    float lsum = 0.f;
    for (int j = tid; j < B_; j += 256) {
        if (labels[j] != li) {
            float daa = 0.f;
#pragma unroll
            for (int p = 0; p < P_; p++)
                daa += bf2f(pd[(size_t)p * B_ * B_ + (size_t)i * B_ + j]);
            float v = di + dap[j] - daa + MARGIN_;
            lsum += fmaxf(v, 0.f);
        }
    }
    for (int o = 32; o; o >>= 1) lsum += __shfl_down(lsum, o, 64);
    __shared__ float red[4];
    int wid = tid >> 6, lane = tid & 63;
    if (lane == 0) red[wid] = lsum;
    __syncthreads();
    if (tid == 0) atomicAdd(possum, red[0] + red[1] + red[2] + red[3]);
}

__global__ void k_finalize(const float* possum, const float* negcnt, float* out) {
    out[0] = possum[0] / negcnt[0];
}

// ---------------- launch ----------------
extern "C" void kernel_launch(void* const* d_in, const int* in_sizes, int n_in,
                              void* d_out, int out_size, void* d_ws, size_t ws_size,
                              hipStream_t stream) {
    const float* feats = (const float*)d_in[0];
    const int* labels  = (const int*)d_in[1];
    float* out = (float*)d_out;

    char* w = (char*)d_ws;
    float* countsf = (float*)(w + OFF_COUNTS);
    int* offs      = (int*)(w + OFF_OFFS);
    int* perm      = (int*)(w + OFF_PERM);
    float* negcnt  = (float*)(w + OFF_NEG);
    float* possum  = (float*)(w + OFF_POS);
    float* S       = (float*)(w + OFF_S);
    float* sq      = (float*)(w + OFF_SQ);
    float* dap     = (float*)(w + OFF_DAP);
    unsigned char* fb = (unsigned char*)(w + OFF_FB);
    u16* pd        = (u16*)(w + OFF_PD);

    // zero possum (at OFF_POS) and S (at OFF_S) in one memset
    hipMemsetAsync(w + OFF_POS, 0, (OFF_S - OFF_POS) + (size_t)B_ * P_ * 4, stream);

    k_counts<<<1, 256, 0, stream>>>(labels, countsf, offs, perm, negcnt);
    k_rowstats<<<B_, 256, 0, stream>>>(feats, fb, sq);
    k_pairs<<<dim3(8, 8, 8), 512, 0, stream>>>(fb, sq, labels, S, pd);
    k_dap<<<NID, 64, 0, stream>>>(S, sq, countsf, offs, perm, dap);
    k_lossred<<<B_, 256, 0, stream>>>(pd, dap, labels, possum);
    k_finalize<<<1, 1, 0, stream>>>(possum, negcnt, out);
}